// Round 9
// baseline (280.322 us; speedup 1.0000x reference)
//
#include <hip/hip_runtime.h>
#include <stdint.h>

#define N_NODES 50000
#define CIN 128
#define CMID 128
#define COUT 32
#define KNB 27
#define EPSV 1e-5f

typedef __attribute__((ext_vector_type(4))) float f4v;
typedef __attribute__((ext_vector_type(8))) short s8v;
typedef __attribute__((ext_vector_type(4))) short s4v;

__device__ __forceinline__ unsigned short f2bf(float f) {
  union { float f; uint32_t u; } v; v.f = f;
  return (unsigned short)((v.u + 0x7FFFu + ((v.u >> 16) & 1u)) >> 16);  // RNE
}
__device__ __forceinline__ float bf2f(short s) {
  return __uint_as_float(((uint32_t)(uint16_t)s) << 16);
}

__device__ __forceinline__ f4v mfma16(s8v a, s8v b, f4v c) {
  return __builtin_amdgcn_mfma_f32_16x16x32_bf16(a, b, c, 0, 0, 0);
}

// async global->LDS, 16B/lane; dest wave-uniform base + lane*16, src per-lane.
__device__ __forceinline__ void gload_lds16(const void* g, void* lds) {
  __builtin_amdgcn_global_load_lds(
      (const __attribute__((address_space(1))) uint32_t*)(uintptr_t)g,
      (__attribute__((address_space(3))) uint32_t*)(uint32_t)(uintptr_t)lds,
      16, 0, 0);
}

// inline int64-vs-int32 detection (hi words of first 16 entries all 0/-1)
__device__ __forceinline__ bool neigh_is64(const void* neigh) {
  const int* p = (const int*)neigh;
  int ok = 1;
#pragma unroll
  for (int i = 0; i < 16; ++i) {
    int hi = p[2 * i + 1];
    if (hi != 0 && hi != -1) ok = 0;
  }
  return ok != 0;
}

// ---------------------------------------------------------------- transpose -
// neighT[k][row] int32 (empty -> N_NODES), via LDS tile transpose (coalesced).
__global__ __launch_bounds__(256) void k_transpose(
    const void* __restrict__ neigh, int* __restrict__ neighT)
{
  __shared__ int tT[KNB][257];
  const int r0 = blockIdx.x * 256;
  const bool is64 = neigh_is64(neigh);
  const int tid = threadIdx.x;
  for (int e = tid; e < 256 * KNB; e += 256) {
    int r = e / KNB, k = e - r * KNB;
    if (r0 + r < N_NODES) {
      long long v = is64 ? ((const long long*)neigh)[(size_t)r0 * KNB + e]
                         : (long long)((const int*)neigh)[(size_t)r0 * KNB + e];
      tT[k][r] = (v < 0) ? N_NODES : (int)v;
    }
  }
  __syncthreads();
  for (int e = tid; e < KNB * 256; e += 256) {
    int k = e >> 8, r = e & 255;
    if (r0 + r < N_NODES) neighT[(size_t)k * N_NODES + r0 + r] = tT[k][r];
  }
}

// ---------------------------------------------------------------- prep_x ----
// xb[(N+1)][128] bf16 (row N zeros); zero gsums.
__global__ __launch_bounds__(256) void k_prep_x(
    const float* __restrict__ data, short* __restrict__ xb,
    float* __restrict__ gsums)
{
  const int TOT0 = (N_NODES + 1) * (CIN / 4);
  int gtid = blockIdx.x * 256 + threadIdx.x;
  int stride = gridDim.x * 256;
  for (int i = gtid; i < TOT0; i += stride) {
    int row = i >> 5, c4 = i & 31;
    s4v o = {};
    if (row < N_NODES) {
      f4v v = *(const f4v*)(data + (size_t)row * CIN + c4 * 4);
      o[0] = (short)f2bf(v[0]); o[1] = (short)f2bf(v[1]);
      o[2] = (short)f2bf(v[2]); o[3] = (short)f2bf(v[3]);
    }
    *(s4v*)(xb + (size_t)row * CIN + c4 * 4) = o;
  }
  if (gtid < 64) gsums[gtid] = 0.0f;
}

// ---------------------------------------------------------------- prep_w ----
// Per-k LDS transpose of W1/W2 -> fragment order, coalesced.
//  wt1f chunk ((k*4+kc)*8+n)*64+l = 8 bf16 {W1[k][kc*32+(l>>4)*8+e][n*16+(l&15)]}
//  wt2f chunk ((2k+t2)*4+kc)*64+l = 8 bf16 {W2[k][kc*32+(l>>4)*8+e][t2*16+(l&15)]}
//   (54-fragment column layout for the projection GEMM: col = t*16+lr, t=2k+t2)
__global__ __launch_bounds__(256) void k_prep_w(
    const float* __restrict__ W1, const float* __restrict__ W2,
    short* __restrict__ wt1f, short* __restrict__ wt2f)
{
  __shared__ short T1[128][136];   // T1[cout][cin]
  __shared__ short T2[32][136];    // T2[cout][cin]
  const int k = blockIdx.x;        // 0..26
  const int tid = threadIdx.x;

  const float* w1p = W1 + (size_t)k * (CIN * CMID);
  for (int i = tid; i < CIN * CMID / 4; i += 256) {     // coalesced 16B reads
    int c = i >> 5, d4 = i & 31;                        // c=cin, d=cout
    f4v v = *(const f4v*)(w1p + c * CMID + d4 * 4);
#pragma unroll
    for (int j = 0; j < 4; ++j) T1[d4 * 4 + j][c] = (short)f2bf(v[j]);
  }
  const float* w2p = W2 + (size_t)k * (CMID * COUT);
  for (int i = tid; i < CMID * COUT / 4; i += 256) {
    int c = i >> 3, d4 = i & 7;
    f4v v = *(const f4v*)(w2p + c * COUT + d4 * 4);
#pragma unroll
    for (int j = 0; j < 4; ++j) T2[d4 * 4 + j][c] = (short)f2bf(v[j]);
  }
  __syncthreads();

  for (int q = tid; q < 2048; q += 256) {               // wt1f
    int l = q & 63, n = (q >> 6) & 7, kc = q >> 9;
    int cin0 = kc * 32 + ((l >> 4) << 3), cout = n * 16 + (l & 15);
    s8v v = *(const s8v*)&T1[cout][cin0];
    *(s8v*)(wt1f + ((size_t)k * 2048 + q) * 8) = v;
  }
  for (int q = tid; q < 512; q += 256) {                // wt2f (proj layout)
    int l = q & 63, kc = (q >> 6) & 3, t2 = q >> 8;
    int cin0 = kc * 32 + ((l >> 4) << 3), cout = t2 * 16 + (l & 15);
    s8v v = *(const s8v*)&T2[cout][cin0];
    int chunk = (2 * k + t2) * 4 + kc;
    *(s8v*)(wt2f + ((size_t)chunk << 9) + l * 8) = v;
  }
}

// ---------------------------------------------------------------- conv1 -----
// r4 structure (best measured): M_block=128, 4 waves (wave = 32 rows x 128
// cols), BK=64, kh-split 2. B: LDS dbuf via global_load_lds. A: gather->regs,
// ds_write to wave-private swizzled LDS; one barrier per half-k step.
__global__ __launch_bounds__(256, 2) void k_conv1(
    const short* __restrict__ xb, const int* __restrict__ neighT,
    const short* __restrict__ wt1f, short* __restrict__ x1p)
{
  __shared__ short Bs[2][8192];        // 2 x 16KB
  __shared__ short As[4][2][2048];     // per-wave 2 x 4KB (32 rows x 128B)
  const int tid = threadIdx.x;
  const int l = tid & 63, w = tid >> 6;
  const int bx = blockIdx.x;
  const int kh = (bx >= 391) ? 1 : 0;
  const int rb = kh ? bx - 391 : bx;
  const int rw = rb * 128 + w * 32;    // wave's first row
  const int k0 = kh ? 13 : 0, k1 = kh ? 27 : 13;
  const int lr = l & 15, lho = l >> 4; // frag row / 8-elem group
  const int l8 = l >> 3, ls = l & 7;   // gather: row-in-8 / 16B slot

  f4v acc[2][8] = {};
  int idx[4], idxn[4];
  s8v ga[4];

  auto loadIdx = [&](int* id, int k) {
#pragma unroll
    for (int q = 0; q < 4; ++q) {
      int r = rw + q * 8 + l8; if (r >= N_NODES) r = N_NODES - 1;
      id[q] = neighT[(size_t)k * N_NODES + r];
    }
  };
  auto stageB = [&](int buf, int k, int h) {
    const short* src = wt1f + ((size_t)(k * 4 + h * 2) * 8) * 512 + l * 8;
#pragma unroll
    for (int j = 0; j < 4; ++j)
      gload_lds16(src + (w * 4 + j) * 512, &Bs[buf][(w * 4 + j) * 512]);
  };
  auto gatherA = [&](const int* id, int h) {
#pragma unroll
    for (int q = 0; q < 4; ++q)
      ga[q] = *(const s8v*)(xb + (size_t)id[q] * CIN + h * 64 + ls * 8);
  };
  auto writeA = [&](int buf) {
#pragma unroll
    for (int q = 0; q < 4; ++q)
      *(s8v*)&As[w][buf][(q * 8 + l8) * 64 + ((ls ^ l8) * 8)] = ga[q];
  };
  auto compute = [&](int cb) {
#pragma unroll
    for (int kc = 0; kc < 2; ++kc) {
      s8v af[2];
#pragma unroll
      for (int rg = 0; rg < 2; ++rg) {
        int row = rg * 16 + lr;
        af[rg] = *(const s8v*)&As[w][cb][row * 64 + (((kc * 4 + lho) ^ (lr & 7)) * 8)];
      }
#pragma unroll
      for (int n = 0; n < 8; ++n) {
        s8v bf = *(const s8v*)&Bs[cb][(kc * 8 + n) * 512 + l * 8];
        acc[0][n] = mfma16(af[0], bf, acc[0][n]);
        acc[1][n] = mfma16(af[1], bf, acc[1][n]);
      }
    }
  };

  loadIdx(idx, k0);
  stageB(0, k0, 0);
  gatherA(idx, 0);
  __syncthreads();
  writeA(0);

  int cur = 0;
  for (int k = k0; k < k1; ++k) {
    const bool more = (k + 1 < k1);
    stageB(cur ^ 1, k, 1);
    gatherA(idx, 1);
    if (more) loadIdx(idxn, k + 1);
    compute(cur);
    __syncthreads();
    writeA(cur ^ 1);
    cur ^= 1;
    if (more) { stageB(cur ^ 1, k + 1, 0); gatherA(idxn, 0); }
    compute(cur);
    __syncthreads();
    if (more) {
      writeA(cur ^ 1);
#pragma unroll
      for (int q = 0; q < 4; ++q) idx[q] = idxn[q];
    }
    cur ^= 1;
  }

  short* xp = x1p + (size_t)kh * N_NODES * CMID;
#pragma unroll
  for (int rg = 0; rg < 2; ++rg) {
#pragma unroll
    for (int j = 0; j < 4; ++j) {
      int grow = rw + rg * 16 + lho * 4 + j;
      if (grow < N_NODES) {
#pragma unroll
        for (int n = 0; n < 8; ++n)
          xp[(size_t)grow * CMID + n * 16 + lr] = (short)f2bf(acc[rg][n][j]);
      }
    }
  }
}

// ---------------------------------------------------------------- sum -------
__global__ __launch_bounds__(256) void k_sum(
    const short* __restrict__ x1p, const float* __restrict__ b1,
    float* __restrict__ gsums)
{
  __shared__ float sh[64];
  const int tid = threadIdx.x;
  if (tid < 64) sh[tid] = 0.0f;
  __syncthreads();
  const int g = tid & 31;
  const short* p0 = x1p;
  const short* p1 = x1p + (size_t)N_NODES * CMID;
  f4v bv = *(const f4v*)(b1 + g * 4);
  float s = 0.f, ss = 0.f;
  for (int r = blockIdx.x * 8 + (tid >> 5); r < N_NODES; r += gridDim.x * 8) {
    s4v v0 = *(const s4v*)(p0 + (size_t)r * CMID + g * 4);
    s4v v1 = *(const s4v*)(p1 + (size_t)r * CMID + g * 4);
#pragma unroll
    for (int e = 0; e < 4; ++e) {
      float x = bf2f(v0[e]) + bf2f(v1[e]) + bv[e];
      s += x; ss += x * x;
    }
  }
  s += __shfl_xor(s, 32); ss += __shfl_xor(ss, 32);
  if ((tid & 32) == 0) { atomicAdd(&sh[g], s); atomicAdd(&sh[32 + g], ss); }
  __syncthreads();
  if (tid < 64) atomicAdd(&gsums[tid], sh[tid]);
}

// ---------------------------------------------------------------- GN+SiLU ---
__global__ __launch_bounds__(256) void k_gnsilu(
    const short* __restrict__ x1p, const float* __restrict__ b1,
    const float* __restrict__ gsums, const float* __restrict__ gn_w,
    const float* __restrict__ gn_b, short* __restrict__ xnb)
{
  const float invc = 1.0f / (N_NODES * 4.0f);
  const short* p0 = x1p;
  const short* p1 = x1p + (size_t)N_NODES * CMID;
  int gtid = blockIdx.x * 256 + threadIdx.x;
  int stride = gridDim.x * 256;
  const int TOT = N_NODES * (CMID / 4);
  for (int i = gtid; i < TOT; i += stride) {
    int row = i >> 5, g = i & 31;
    float mean = gsums[g] * invc;
    float var = gsums[32 + g] * invc - mean * mean;
    float rs = rsqrtf(var + EPSV);
    s4v v0 = *(const s4v*)(p0 + (size_t)row * CMID + g * 4);
    s4v v1 = *(const s4v*)(p1 + (size_t)row * CMID + g * 4);
    f4v bv = *(const f4v*)(b1 + g * 4);
    f4v wv = *(const f4v*)(gn_w + g * 4);
    f4v gv = *(const f4v*)(gn_b + g * 4);
    s4v o;
#pragma unroll
    for (int e = 0; e < 4; ++e) {
      float x = bf2f(v0[e]) + bf2f(v1[e]) + bv[e];
      float xn = (x - mean) * rs * wv[e] + gv[e];
      float y = xn / (1.0f + __expf(-xn));
      o[e] = (short)f2bf(y);
    }
    *(s4v*)(xnb + (size_t)row * CMID + g * 4) = o;
  }
}

// ---------------------------------------------------------------- proj ------
// Dense GEMM xn[50000,128] x W2cat[128, 16*T0..16*(T0+NT)) -> cbuf bf16.
// NO LDS, NO barriers: W2 fragments read straight from global (216KB, L1/L2-
// broadcast across waves); A in 8 regs; pure dataflow -> high occupancy.
template<int T0, int NT>
__global__ __launch_bounds__(256) void k_proj(
    const short* __restrict__ xnb, const short* __restrict__ wt2f,
    short* __restrict__ cbuf)
{
  const int tid = threadIdx.x;
  const int l = tid & 63, w = tid >> 6;
  const int rw = blockIdx.x * 128 + w * 32;
  const int lr = l & 15, lho = l >> 4;
  const int NC = NT * 16;

  s8v a[2][4];
#pragma unroll
  for (int rs = 0; rs < 2; ++rs) {
    int row = rw + rs * 16 + lr; if (row >= N_NODES) row = N_NODES - 1;
    const short* p = xnb + (size_t)row * CMID + lho * 8;
#pragma unroll
    for (int kc = 0; kc < 4; ++kc) a[rs][kc] = *(const s8v*)(p + kc * 32);
  }

#pragma unroll 2
  for (int t = 0; t < NT; ++t) {
    const short* wp = wt2f + ((size_t)((T0 + t) * 4) << 9) + l * 8;
    s8v bf[4];
#pragma unroll
    for (int kc = 0; kc < 4; ++kc) bf[kc] = *(const s8v*)(wp + (kc << 9));
    f4v acc[2] = {};
#pragma unroll
    for (int kc = 0; kc < 4; ++kc) {
      acc[0] = mfma16(a[0][kc], bf[kc], acc[0]);
      acc[1] = mfma16(a[1][kc], bf[kc], acc[1]);
    }
#pragma unroll
    for (int rs = 0; rs < 2; ++rs) {
#pragma unroll
      for (int j = 0; j < 4; ++j) {
        int row = rw + rs * 16 + lho * 4 + j;
        if (row < N_NODES)
          cbuf[(size_t)row * NC + t * 16 + lr] = (short)f2bf(acc[rs][j]);
      }
    }
  }
}

// ---------------------------------------------------------------- gather2 ---
// out[n][j] (=bias+ / +=) sum_k cbuf[neigh[n][k]][k*32+j]. 8 lanes/node,
// 8B/lane (one 64B line per (n,k)). Unconditional loads + mask -> full ILP.
template<int INIT, int KC, int KSTART>
__global__ __launch_bounds__(256) void k_gather2(
    const short* __restrict__ cbuf, const void* __restrict__ neigh,
    const float* __restrict__ b2, float* __restrict__ out)
{
  const int tid = threadIdx.x;
  const int n = blockIdx.x * 32 + (tid >> 3);
  const int l8 = tid & 7;
  if (n >= N_NODES) return;
  const bool is64 = neigh_is64(neigh);
  const int NC = KC * 32;

  int id[KC]; float msk[KC];
#pragma unroll
  for (int k = 0; k < KC; ++k) {
    long long v = is64 ? ((const long long*)neigh)[(size_t)n * KNB + KSTART + k]
                       : (long long)((const int*)neigh)[(size_t)n * KNB + KSTART + k];
    msk[k] = (v >= 0) ? 1.0f : 0.0f;
    id[k] = (v >= 0) ? (int)v : 0;
  }
  f4v acc;
  if (INIT) acc = *(const f4v*)(b2 + l8 * 4);
  else      acc = *(const f4v*)(out + (size_t)n * COUT + l8 * 4);
  s4v cv[KC];
#pragma unroll
  for (int k = 0; k < KC; ++k)
    cv[k] = *(const s4v*)(cbuf + (size_t)id[k] * NC + k * 32 + l8 * 4);
#pragma unroll
  for (int k = 0; k < KC; ++k) {
#pragma unroll
    for (int e = 0; e < 4; ++e) acc[e] += msk[k] * bf2f(cv[k][e]);
  }
  *(f4v*)(out + (size_t)n * COUT + l8 * 4) = acc;
}

// ---------------------------------------------------------------- launch ----
extern "C" void kernel_launch(void* const* d_in, const int* in_sizes, int n_in,
                              void* d_out, int out_size, void* d_ws, size_t ws_size,
                              hipStream_t stream) {
  const float* data = (const float*)d_in[0];
  const void* neigh = d_in[1];
  const float* W1   = (const float*)d_in[2];
  const float* b1   = (const float*)d_in[3];
  const float* gn_w = (const float*)d_in[4];
  const float* gn_b = (const float*)d_in[5];
  const float* W2   = (const float*)d_in[6];
  const float* b2   = (const float*)d_in[7];

  // region0 (44.8MB): conv1-phase [xb|wt1f|neighT|x1p], later aliased by cbuf
  char* p = (char*)d_ws;
  char* r0 = p;
  short* xb   = (short*)p; p += (size_t)(N_NODES + 1) * CIN * 2;   // 12.80MB
  short* wt1f = (short*)p; p += (size_t)KNB * CMID * CIN * 2;      // 0.88MB
  int*   neighT = (int*)p; p += (size_t)KNB * N_NODES * 4;         // 5.40MB
  short* x1p  = (short*)p; p += (size_t)2 * N_NODES * CMID * 2;    // 25.60MB
  short* cbuf = (short*)r0;                 // pass max: 50000*448*2 = 44.8MB
  p = r0 + (size_t)N_NODES * 448 * 2;       // 44,800,000 (>= layout above)
  // region1: live across both phases
  short* xnb  = (short*)p; p += (size_t)(N_NODES + 1) * CMID * 2;  // 12.80MB
  short* wt2f = (short*)p; p += (size_t)54 * 4 * 64 * 8 * 2;       // 0.22MB
  float* gsums = (float*)p;

  k_transpose<<<(N_NODES + 255) / 256, 256, 0, stream>>>(neigh, neighT);
  k_prep_x<<<2048, 256, 0, stream>>>(data, xb, gsums);
  k_prep_w<<<KNB, 256, 0, stream>>>(W1, W2, wt1f, wt2f);
  k_conv1<<<782, 256, 0, stream>>>(xb, neighT, wt1f, x1p);
  k_sum<<<391, 256, 0, stream>>>(x1p, b1, gsums);
  k_gnsilu<<<1563, 256, 0, stream>>>(x1p, b1, gsums, gn_w, gn_b, xnb);
  // conv2 = projection-first (dense GEMM, L2-resident W2), two column passes
  k_proj<0, 28><<<391, 256, 0, stream>>>(xnb, wt2f, cbuf);           // k 0..13
  k_gather2<1, 14, 0><<<1563, 256, 0, stream>>>(cbuf, neigh, b2, (float*)d_out);
  k_proj<28, 26><<<391, 256, 0, stream>>>(xnb, wt2f, cbuf);          // k 14..26
  k_gather2<0, 13, 14><<<1563, 256, 0, stream>>>(cbuf, neigh, b2, (float*)d_out);
}